// Round 12
// baseline (187.659 us; speedup 1.0000x reference)
//
#include <hip/hip_runtime.h>
#include <hip/hip_bf16.h>

#define N_NODES 50000
#define N_EDGES 400000
#define FIN     128
#define HD      512
#define SLOPE   0.2f

typedef __hip_bfloat16 bf16;
typedef __bf16 bf16x8 __attribute__((ext_vector_type(8)));
typedef __bf16 bf16x4 __attribute__((ext_vector_type(4)));
typedef __bf16 bf16x2 __attribute__((ext_vector_type(2)));
typedef float  f32x4  __attribute__((ext_vector_type(4)));
typedef float  f32x2  __attribute__((ext_vector_type(2)));

// ---------------- sentinel (workspace too small diagnostic) ----------------
__global__ void sentinel_k(float* out, int n) {
    int i = blockIdx.x * 256 + threadIdx.x;
    if (i < n) out[i] = 12288.0f;
}

// ---- prep: zero deg | Wfrag (fragment-ordered [W1;Wres1]) | tab epilogue constants | wl/wr ----
// Wfrag[unit][lane][8bf16], unit = (head*8+ct)*8+ks: fragment = Wcomb[gc=tile*16+cl][k=ks*32+rg*8..+8]
// tab[gc][8] = {hscale, hshift, W2[gc][0..2], Wres2[gc][0..2]};  h = ELU(z*hscale + hshift)
__global__ __launch_bounds__(256) void prep_k(const float* __restrict__ W1, const float* __restrict__ Wres1,
                                              const float* __restrict__ al1, const float* __restrict__ ar1,
                                              const float* __restrict__ W2, const float* __restrict__ Wres2,
                                              const float* __restrict__ b1,
                                              const float* __restrict__ bnm, const float* __restrict__ bnv,
                                              const float* __restrict__ bng, const float* __restrict__ bnb,
                                              bf16* __restrict__ Wfrag, float* __restrict__ tab,
                                              float* __restrict__ wl, float* __restrict__ wr,
                                              int* __restrict__ deg) {
    int b = blockIdx.x;
    if (b < 196) {
        int i = b * 256 + threadIdx.x;
        if (i < N_NODES) deg[i] = 0;
        return;
    }
    b -= 196;
    if (b < 64) {                        // Wfrag: 16384 fragments of 16B
        int f = b * 256 + threadIdx.x;   // fragment index
        int lane = f & 63, unit = f >> 6;
        int tile = unit >> 3, ks = unit & 7;
        int cl = lane & 15, rg = lane >> 4;
        int gc = tile * 16 + cl;
        int k0 = ks * 32 + rg * 8;
        bf16x8 v;
#pragma unroll
        for (int j = 0; j < 8; ++j) {
            int kk = k0 + j;
            float x = (kk < 128) ? W1[kk * HD + gc] : Wres1[(kk - 128) * HD + gc];
            v[j] = (__bf16)x;
        }
        *reinterpret_cast<bf16x8*>(reinterpret_cast<char*>(Wfrag) + (size_t)f * 16) = v;
        return;
    }
    b -= 64;
    if (b < 16) {                        // tab
        int i = b * 256 + threadIdx.x;   // 0..4095
        int gc = i >> 3, c = i & 7;
        float v;
        if (c < 2) {
            float rs = rsqrtf(bnv[gc] + 1e-5f) * bng[gc];
            v = (c == 0) ? rs : (b1[gc] - bnm[gc]) * rs + bnb[gc];
        } else if (c < 5) {
            v = W2[gc * 3 + (c - 2)];
        } else {
            v = Wres2[gc * 3 + (c - 5)];
        }
        tab[i] = v;
        return;
    }
    b -= 16;                             // wl/wr: 2 blocks cover 128k x 4h
    int i = b * 256 + threadIdx.x;
    int k = i >> 2, h = i & 3;
    float sl = 0.f, sr = 0.f;
    for (int d = 0; d < 128; ++d) {
        float w = W1[k * HD + h * 128 + d];
        sl += w * al1[h * 128 + d];
        sr += w * ar1[h * 128 + d];
    }
    wl[k * 4 + h] = sl;
    wr[k * 4 + h] = sr;
}

// ---------------- el/er per node (wave-per-node) + Xb bf16 convert ----------------
__global__ __launch_bounds__(256) void eler_k(const float* __restrict__ X,
                                              const float* __restrict__ wl, const float* __restrict__ wr,
                                              float* __restrict__ el, float* __restrict__ er,
                                              bf16* __restrict__ Xb) {
    int w = threadIdx.x >> 6, lane = threadIdx.x & 63;
    int n = blockIdx.x * 4 + w;
    float x1 = X[(size_t)n * FIN + lane];
    float x2 = X[(size_t)n * FIN + 64 + lane];
    Xb[(size_t)n * FIN + lane] = __float2bfloat16(x1);
    Xb[(size_t)n * FIN + 64 + lane] = __float2bfloat16(x2);
    float pl[4], pr[4];
#pragma unroll
    for (int h = 0; h < 4; ++h) {
        pl[h] = x1 * wl[lane * 4 + h] + x2 * wl[(lane + 64) * 4 + h];
        pr[h] = x1 * wr[lane * 4 + h] + x2 * wr[(lane + 64) * 4 + h];
    }
#pragma unroll
    for (int off = 32; off > 0; off >>= 1) {
#pragma unroll
        for (int h = 0; h < 4; ++h) {
            pl[h] += __shfl_xor(pl[h], off);
            pr[h] += __shfl_xor(pr[h], off);
        }
    }
    if (lane == 0) {
        *reinterpret_cast<float4*>(el + (size_t)n * 4) = make_float4(pl[0], pl[1], pl[2], pl[3]);
        *reinterpret_cast<float4*>(er + (size_t)n * 4) = make_float4(pr[0], pr[1], pr[2], pr[3]);
    }
}

// ---------------- CSR build ----------------
__global__ void hist_k(const int* __restrict__ dst, int* __restrict__ deg) {
    int e = blockIdx.x * 256 + threadIdx.x;
    if (e < N_EDGES) atomicAdd(&deg[dst[e]], 1);
}

__global__ __launch_bounds__(256) void scan1_k(const int* __restrict__ deg,
                                               int* __restrict__ rowptr, int* __restrict__ blksum) {
    __shared__ int wsum[4];
    int t = threadIdx.x, b = blockIdx.x;
    int i = b * 256 + t;
    int v = (i < N_NODES) ? deg[i] : 0;
    int lane = t & 63, w = t >> 6;
    int x = v;
#pragma unroll
    for (int off = 1; off < 64; off <<= 1) {
        int y = __shfl_up(x, off);
        if (lane >= off) x += y;
    }
    if (lane == 63) wsum[w] = x;
    __syncthreads();
    int wadd = 0;
    if (w > 0) wadd += wsum[0];
    if (w > 1) wadd += wsum[1];
    if (w > 2) wadd += wsum[2];
    int incl = x + wadd;
    if (i < N_NODES) rowptr[i] = incl - v;
    if (t == 255) blksum[b] = incl;
}

__global__ __launch_bounds__(256) void scan2_k(int* __restrict__ blksum) {
    __shared__ int wsum[4];
    int t = threadIdx.x;
    int v = (t < 196) ? blksum[t] : 0;
    int lane = t & 63, w = t >> 6;
    int x = v;
#pragma unroll
    for (int off = 1; off < 64; off <<= 1) {
        int y = __shfl_up(x, off);
        if (lane >= off) x += y;
    }
    if (lane == 63) wsum[w] = x;
    __syncthreads();
    int wadd = 0;
    if (w > 0) wadd += wsum[0];
    if (w > 1) wadd += wsum[1];
    if (w > 2) wadd += wsum[2];
    if (t < 196) blksum[t] = x + wadd - v;
}

__global__ __launch_bounds__(256) void scan3_k(const int* __restrict__ blksum,
                                               int* __restrict__ rowptr, int* __restrict__ cursor) {
    int b = blockIdx.x;
    int i = b * 256 + threadIdx.x;
    if (i < N_NODES) {
        int v = rowptr[i] + blksum[b];
        rowptr[i] = v;
        cursor[i] = v;
    }
    if (i == 0) rowptr[N_NODES] = N_EDGES;
}

__global__ void fill_k(const int* __restrict__ src, const int* __restrict__ dst,
                       int* __restrict__ cursor, int* __restrict__ csr) {
    int e = blockIdx.x * 256 + threadIdx.x;
    if (e < N_EDGES) {
        int pos = atomicAdd(&cursor[dst[e]], 1);
        csr[pos] = src[e];
    }
}

// ---------------- X-space aggregation v2: 8-wide unclamped batches + packed FMA ----------------
// AGG[n][h*128+c] = (1/den_h) sum_e p^h_e Xb[src_e][c]; lane owns 2 channels (4B), all 4 heads.
__global__ __launch_bounds__(256) void aggX_k(const int* __restrict__ rowptr, const int* __restrict__ csr,
                                              const float* __restrict__ el, const float* __restrict__ er,
                                              const bf16* __restrict__ Xb, bf16* __restrict__ AGGb) {
    __shared__ int    ssrc[4][64];
    __shared__ float4 spe4[4][64];

    const int w = threadIdx.x >> 6, lane = threadIdx.x & 63;
    const int n = blockIdx.x * 4 + w;
    const int beg = rowptr[n];
    const int deg = rowptr[n + 1] - beg;
    const float4 ern = *reinterpret_cast<const float4*>(er + (size_t)n * 4);
    const char* Xbc = reinterpret_cast<const char*>(Xb);

    f32x2 acc[4] = {{0.f,0.f},{0.f,0.f},{0.f,0.f},{0.f,0.f}};
    float4 den = make_float4(0.f, 0.f, 0.f, 0.f);

    for (int base = 0; base < deg; base += 64) {
        const int cnt = min(64, deg - base);
        if (lane < cnt) {
            int s = csr[beg + base + lane];
            ssrc[w][lane] = s;
            float4 e4 = *reinterpret_cast<const float4*>(el + (size_t)s * 4);
            float4 p; float e;
            e = e4.x + ern.x; e = e > 0.f ? e : SLOPE * e; p.x = __expf(e);
            e = e4.y + ern.y; e = e > 0.f ? e : SLOPE * e; p.y = __expf(e);
            e = e4.z + ern.z; e = e > 0.f ? e : SLOPE * e; p.z = __expf(e);
            e = e4.w + ern.w; e = e > 0.f ? e : SLOPE * e; p.w = __expf(e);
            den.x += p.x; den.y += p.y; den.z += p.z; den.w += p.w;
            spe4[w][lane] = p;
        }
        asm volatile("s_waitcnt lgkmcnt(0)" ::: "memory");
        int jj = 0;
        // full 8-wide batches: no clamping, 8 outstanding loads
        for (; jj + 8 <= cnt; jj += 8) {
            unsigned xv[8]; float4 pk[8];
#pragma unroll
            for (int k2 = 0; k2 < 8; ++k2) {
                int s = ssrc[w][jj + k2];
                xv[k2] = *reinterpret_cast<const unsigned*>(Xbc + (size_t)s * 256 + lane * 4);
                pk[k2] = spe4[w][jj + k2];
            }
#pragma unroll
            for (int k2 = 0; k2 < 8; ++k2) {
                f32x2 x2 = {__uint_as_float(xv[k2] << 16), __uint_as_float(xv[k2] & 0xffff0000u)};
                acc[0] += pk[k2].x * x2;
                acc[1] += pk[k2].y * x2;
                acc[2] += pk[k2].z * x2;
                acc[3] += pk[k2].w * x2;
            }
        }
        // scalar tail
        for (; jj < cnt; ++jj) {
            int s = ssrc[w][jj];
            unsigned xv = *reinterpret_cast<const unsigned*>(Xbc + (size_t)s * 256 + lane * 4);
            float4 p = spe4[w][jj];
            f32x2 x2 = {__uint_as_float(xv << 16), __uint_as_float(xv & 0xffff0000u)};
            acc[0] += p.x * x2;
            acc[1] += p.y * x2;
            acc[2] += p.z * x2;
            acc[3] += p.w * x2;
        }
        asm volatile("s_waitcnt lgkmcnt(0)" ::: "memory");   // WAR guard before next chunk
    }

#pragma unroll
    for (int off = 32; off > 0; off >>= 1) {
        den.x += __shfl_xor(den.x, off);
        den.y += __shfl_xor(den.y, off);
        den.z += __shfl_xor(den.z, off);
        den.w += __shfl_xor(den.w, off);
    }
    float inv[4] = {0.f, 0.f, 0.f, 0.f};
    if (deg > 0) {
        inv[0] = 1.f / den.x; inv[1] = 1.f / den.y;
        inv[2] = 1.f / den.z; inv[3] = 1.f / den.w;
    }
#pragma unroll
    for (int h = 0; h < 4; ++h) {
        bf16x2 v = {(__bf16)(acc[h][0] * inv[h]), (__bf16)(acc[h][1] * inv[h])};
        *reinterpret_cast<bf16x2*>(AGGb + (size_t)n * 512 + h * 128 + lane * 2) = v;
    }
}

// ---------------- fused GEMM2 v3: coalesced Wfrag + tab epilogue ----------------
__global__ __launch_bounds__(256) void gemm2_k(
    const bf16* __restrict__ Xb, const bf16* __restrict__ AGGb,
    const bf16* __restrict__ Wfrag, const float* __restrict__ tab,
    const float* __restrict__ al2, const float* __restrict__ ar2,
    float* __restrict__ node2) {
    __shared__ __align__(16) char XS[32 * 256];    // 8 KB
    __shared__ __align__(16) char AGS[32 * 1024];  // 32 KB
    __shared__ float zsum[4][32][6];               // 3 KB

    const int t = threadIdx.x;
    const int w = t >> 6, lane = t & 63;
    const int cl = lane & 15, rg = lane >> 4;
    const int m0 = blockIdx.x * 32;

    // stage X: 32 rows x 256B
#pragma unroll
    for (int j = 0; j < 2; ++j) {
        int L = j * 4096 + t * 16;
        int row = L >> 8, col = L & 255;
        int grow = m0 + row; grow = grow < N_NODES ? grow : N_NODES - 1;
        bf16x8 v = *reinterpret_cast<const bf16x8*>(
            reinterpret_cast<const char*>(Xb) + (size_t)grow * 256 + col);
        int byte = (row * 256 + col) ^ ((row & 7) << 4);
        *reinterpret_cast<bf16x8*>(XS + byte) = v;
    }
    // stage AGG (all heads): 32 rows x 1024B
#pragma unroll
    for (int j = 0; j < 8; ++j) {
        int L = j * 4096 + t * 16;
        int row = L >> 10, col = L & 1023;
        int grow = m0 + row; grow = grow < N_NODES ? grow : N_NODES - 1;
        bf16x8 v = *reinterpret_cast<const bf16x8*>(
            reinterpret_cast<const char*>(AGGb) + (size_t)grow * 1024 + col);
        int byte = (row * 1024 + col) ^ ((row & 7) << 4);
        *reinterpret_cast<bf16x8*>(AGS + byte) = v;
    }
    __syncthreads();

    float z2p[2][3] = {}, r2p[2][3] = {};

#pragma unroll
    for (int ct = 0; ct < 8; ++ct) {
        const int unit = (w * 8 + ct) * 8;
        bf16x8 af[8];
#pragma unroll
        for (int ks = 0; ks < 8; ++ks)
            af[ks] = *reinterpret_cast<const bf16x8*>(
                reinterpret_cast<const char*>(Wfrag) + ((size_t)(unit + ks) * 64 + lane) * 16);
        const int gcl = w * 128 + ct * 16 + rg * 4;
        f32x4 t0[4], t1[4];
#pragma unroll
        for (int i = 0; i < 4; ++i) {
            t0[i] = *reinterpret_cast<const f32x4*>(tab + (size_t)(gcl + i) * 8);
            t1[i] = *reinterpret_cast<const f32x4*>(tab + (size_t)(gcl + i) * 8 + 4);
        }
#pragma unroll
        for (int mt = 0; mt < 2; ++mt) {
            int row = mt * 16 + cl;
            int swz = (row & 7) << 4;
            f32x4 a = {0.f, 0.f, 0.f, 0.f};
            // k 0..127: AGG head w
#pragma unroll
            for (int ks = 0; ks < 4; ++ks) {
                int byte = (row * 1024 + w * 256 + ks * 64 + rg * 16) ^ swz;
                bf16x8 bfr = *reinterpret_cast<const bf16x8*>(AGS + byte);
                a = __builtin_amdgcn_mfma_f32_16x16x32_bf16(af[ks], bfr, a, 0, 0, 0);
            }
            // k 128..255: X
#pragma unroll
            for (int ks = 0; ks < 4; ++ks) {
                int byte = (row * 256 + ks * 64 + rg * 16) ^ swz;
                bf16x8 bfr = *reinterpret_cast<const bf16x8*>(XS + byte);
                a = __builtin_amdgcn_mfma_f32_16x16x32_bf16(af[ks + 4], bfr, a, 0, 0, 0);
            }
#pragma unroll
            for (int i = 0; i < 4; ++i) {
                float hv = a[i] * t0[i][0] + t0[i][1];
                hv = hv > 0.f ? hv : (__expf(hv) - 1.f);
                z2p[mt][0] += hv * t0[i][2]; z2p[mt][1] += hv * t0[i][3]; z2p[mt][2] += hv * t1[i][0];
                r2p[mt][0] += hv * t1[i][1]; r2p[mt][1] += hv * t1[i][2]; r2p[mt][2] += hv * t1[i][3];
            }
        }
    }

    // reduce across rg (4 lanes share node cl per mt)
#pragma unroll
    for (int mt = 0; mt < 2; ++mt)
#pragma unroll
        for (int c = 0; c < 3; ++c) {
            z2p[mt][c] += __shfl_xor(z2p[mt][c], 16);
            z2p[mt][c] += __shfl_xor(z2p[mt][c], 32);
            r2p[mt][c] += __shfl_xor(r2p[mt][c], 16);
            r2p[mt][c] += __shfl_xor(r2p[mt][c], 32);
        }
    if (rg == 0) {
#pragma unroll
        for (int mt = 0; mt < 2; ++mt) {
            int nl = mt * 16 + cl;
            zsum[w][nl][0] = z2p[mt][0]; zsum[w][nl][1] = z2p[mt][1]; zsum[w][nl][2] = z2p[mt][2];
            zsum[w][nl][3] = r2p[mt][0]; zsum[w][nl][4] = r2p[mt][1]; zsum[w][nl][5] = r2p[mt][2];
        }
    }
    __syncthreads();
    if (t < 32) {
        float v[6];
#pragma unroll
        for (int c = 0; c < 6; ++c)
            v[c] = zsum[0][t][c] + zsum[1][t][c] + zsum[2][t][c] + zsum[3][t][c];
        int n = m0 + t;
        if (n < N_NODES) {
            float e2l = v[0] * al2[0] + v[1] * al2[1] + v[2] * al2[2];
            float e2r = v[0] * ar2[0] + v[1] * ar2[1] + v[2] * ar2[2];
            *reinterpret_cast<float4*>(node2 + (size_t)n * 8) = make_float4(v[0], v[1], v[2], e2l);
            *reinterpret_cast<float4*>(node2 + (size_t)n * 8 + 4) = make_float4(v[3], v[4], v[5], e2r);
        }
    }
}

// ---------------- layer-2 aggregation: wave-per-node ----------------
__global__ __launch_bounds__(256) void agg2_k(const int* __restrict__ rowptr, const int* __restrict__ csr,
                                              const float* __restrict__ node2,
                                              const float* __restrict__ b2, float* __restrict__ out) {
    int wv = threadIdx.x >> 6, lane = threadIdx.x & 63;
    int n = blockIdx.x * 4 + wv;
    int beg = rowptr[n], deg = rowptr[n + 1] - beg;
    float ern = node2[(size_t)n * 8 + 7];
    float den = 0.f, a0 = 0.f, a1 = 0.f, a2 = 0.f;
    for (int j = lane; j < deg; j += 64) {
        int s = csr[beg + j];
        float4 v = *reinterpret_cast<const float4*>(node2 + (size_t)s * 8);
        float e = v.w + ern;
        e = e > 0.f ? e : SLOPE * e;
        float p = __expf(e);
        den += p;
        a0 += p * v.x; a1 += p * v.y; a2 += p * v.z;
    }
#pragma unroll
    for (int off = 32; off > 0; off >>= 1) {
        den += __shfl_xor(den, off);
        a0 += __shfl_xor(a0, off); a1 += __shfl_xor(a1, off); a2 += __shfl_xor(a2, off);
    }
    if (lane == 0) {
        float inv = deg > 0 ? 1.f / den : 0.f;
        float4 r = *reinterpret_cast<const float4*>(node2 + (size_t)n * 8 + 4);
        out[(size_t)n * 3 + 0] = a0 * inv + r.x + b2[0];
        out[(size_t)n * 3 + 1] = a1 * inv + r.y + b2[1];
        out[(size_t)n * 3 + 2] = a2 * inv + r.z + b2[2];
    }
}

extern "C" void kernel_launch(void* const* d_in, const int* in_sizes, int n_in,
                              void* d_out, int out_size, void* d_ws, size_t ws_size,
                              hipStream_t stream) {
    const float* X     = (const float*)d_in[0];
    const int*   src   = (const int*)d_in[1];
    const int*   dst   = (const int*)d_in[2];
    const float* W1    = (const float*)d_in[3];
    const float* al1   = (const float*)d_in[4];
    const float* ar1   = (const float*)d_in[5];
    const float* b1    = (const float*)d_in[6];
    const float* Wres1 = (const float*)d_in[7];
    const float* bng   = (const float*)d_in[8];
    const float* bnb   = (const float*)d_in[9];
    const float* bnm   = (const float*)d_in[10];
    const float* bnv   = (const float*)d_in[11];
    const float* W2    = (const float*)d_in[12];
    const float* al2   = (const float*)d_in[13];
    const float* ar2   = (const float*)d_in[14];
    const float* b2    = (const float*)d_in[15];
    const float* Wres2 = (const float*)d_in[16];
    float* out = (float*)d_out;

    char* p = (char*)d_ws;
    auto carve = [&](size_t bytes) -> char* {
        char* r = p;
        p += (bytes + 255) & ~(size_t)255;
        return r;
    };
    bf16*  Wfrag  = (bf16*)carve((size_t)512 * 256 * 2);    // 256 KB fragment-ordered
    float* tab    = (float*)carve((size_t)512 * 8 * 4);     // 16 KB epilogue constants
    float* wl     = (float*)carve((size_t)FIN * 4 * 4);
    float* wr     = (float*)carve((size_t)FIN * 4 * 4);
    float* el     = (float*)carve((size_t)N_NODES * 4 * 4);
    float* er     = (float*)carve((size_t)N_NODES * 4 * 4);
    int*   deg    = (int*)carve((size_t)N_NODES * 4);
    int*   rowptr = (int*)carve((size_t)(N_NODES + 1) * 4);
    int*   cursor = (int*)carve((size_t)N_NODES * 4);
    int*   blksum = (int*)carve((size_t)256 * 4);
    int*   csr    = (int*)carve((size_t)N_EDGES * 4);
    bf16*  Xb     = (bf16*)carve((size_t)N_NODES * FIN * 2);
    bf16*  AGGb   = (bf16*)carve((size_t)N_NODES * 512 * 2);
    float* node2  = (float*)carve((size_t)N_NODES * 8 * 4);
    size_t need = (size_t)(p - (char*)d_ws);
    if (need > ws_size) {
        sentinel_k<<<(out_size + 255) / 256, 256, 0, stream>>>(out, out_size);
        return;
    }

    prep_k<<<196 + 64 + 16 + 2, 256, 0, stream>>>(W1, Wres1, al1, ar1, W2, Wres2, b1,
                                                  bnm, bnv, bng, bnb, Wfrag, tab, wl, wr, deg);
    eler_k<<<N_NODES / 4, 256, 0, stream>>>(X, wl, wr, el, er, Xb);
    hist_k<<<(N_EDGES + 255) / 256, 256, 0, stream>>>(dst, deg);
    scan1_k<<<196, 256, 0, stream>>>(deg, rowptr, blksum);
    scan2_k<<<1, 256, 0, stream>>>(blksum);
    scan3_k<<<196, 256, 0, stream>>>(blksum, rowptr, cursor);
    fill_k<<<(N_EDGES + 255) / 256, 256, 0, stream>>>(src, dst, cursor, csr);
    aggX_k<<<N_NODES / 4, 256, 0, stream>>>(rowptr, csr, el, er, Xb, AGGb);
    gemm2_k<<<(N_NODES + 31) / 32, 256, 0, stream>>>(Xb, AGGb, Wfrag, tab, al2, ar2, node2);
    agg2_k<<<N_NODES / 4, 256, 0, stream>>>(rowptr, csr, node2, b2, out);
}

// Round 13
// 174.086 us; speedup vs baseline: 1.0780x; 1.0780x over previous
//
#include <hip/hip_runtime.h>
#include <hip/hip_bf16.h>

#define N_NODES 50000
#define N_EDGES 400000
#define FIN     128
#define HD      512
#define SLOPE   0.2f

typedef __hip_bfloat16 bf16;
typedef __bf16 bf16x8 __attribute__((ext_vector_type(8)));
typedef __bf16 bf16x4 __attribute__((ext_vector_type(4)));
typedef __bf16 bf16x2 __attribute__((ext_vector_type(2)));
typedef float  f32x4  __attribute__((ext_vector_type(4)));
typedef float  f32x2  __attribute__((ext_vector_type(2)));

// ---------------- sentinel (workspace too small diagnostic) ----------------
__global__ void sentinel_k(float* out, int n) {
    int i = blockIdx.x * 256 + threadIdx.x;
    if (i < n) out[i] = 12288.0f;
}

// ---- prep: zero deg | Wfrag (fragment-ordered [W1;Wres1]) | tab epilogue constants | wl/wr ----
__global__ __launch_bounds__(256) void prep_k(const float* __restrict__ W1, const float* __restrict__ Wres1,
                                              const float* __restrict__ al1, const float* __restrict__ ar1,
                                              const float* __restrict__ W2, const float* __restrict__ Wres2,
                                              const float* __restrict__ b1,
                                              const float* __restrict__ bnm, const float* __restrict__ bnv,
                                              const float* __restrict__ bng, const float* __restrict__ bnb,
                                              bf16* __restrict__ Wfrag, float* __restrict__ tab,
                                              float* __restrict__ wl, float* __restrict__ wr,
                                              int* __restrict__ deg) {
    int b = blockIdx.x;
    if (b < 196) {
        int i = b * 256 + threadIdx.x;
        if (i < N_NODES) deg[i] = 0;
        return;
    }
    b -= 196;
    if (b < 64) {                        // Wfrag: 16384 fragments of 16B
        int f = b * 256 + threadIdx.x;   // fragment index
        int lane = f & 63, unit = f >> 6;
        int tile = unit >> 3, ks = unit & 7;
        int cl = lane & 15, rg = lane >> 4;
        int gc = tile * 16 + cl;
        int k0 = ks * 32 + rg * 8;
        bf16x8 v;
#pragma unroll
        for (int j = 0; j < 8; ++j) {
            int kk = k0 + j;
            float x = (kk < 128) ? W1[kk * HD + gc] : Wres1[(kk - 128) * HD + gc];
            v[j] = (__bf16)x;
        }
        *reinterpret_cast<bf16x8*>(reinterpret_cast<char*>(Wfrag) + (size_t)f * 16) = v;
        return;
    }
    b -= 64;
    if (b < 16) {                        // tab
        int i = b * 256 + threadIdx.x;   // 0..4095
        int gc = i >> 3, c = i & 7;
        float v;
        if (c < 2) {
            float rs = rsqrtf(bnv[gc] + 1e-5f) * bng[gc];
            v = (c == 0) ? rs : (b1[gc] - bnm[gc]) * rs + bnb[gc];
        } else if (c < 5) {
            v = W2[gc * 3 + (c - 2)];
        } else {
            v = Wres2[gc * 3 + (c - 5)];
        }
        tab[i] = v;
        return;
    }
    b -= 16;                             // wl/wr: 2 blocks cover 128k x 4h
    int i = b * 256 + threadIdx.x;
    int k = i >> 2, h = i & 3;
    float sl = 0.f, sr = 0.f;
    for (int d = 0; d < 128; ++d) {
        float w = W1[k * HD + h * 128 + d];
        sl += w * al1[h * 128 + d];
        sr += w * ar1[h * 128 + d];
    }
    wl[k * 4 + h] = sl;
    wr[k * 4 + h] = sr;
}

// ---------------- el/er per node (wave-per-node) + Xb bf16 convert | hist (tail blocks) ----------------
__global__ __launch_bounds__(256) void eler_k(const float* __restrict__ X,
                                              const float* __restrict__ wl, const float* __restrict__ wr,
                                              float* __restrict__ el, float* __restrict__ er,
                                              bf16* __restrict__ Xb,
                                              const int* __restrict__ dst, int* __restrict__ deg) {
    if (blockIdx.x >= N_NODES / 4) {     // histogram part
        int e = (blockIdx.x - N_NODES / 4) * 256 + threadIdx.x;
        if (e < N_EDGES) atomicAdd(&deg[dst[e]], 1);
        return;
    }
    int w = threadIdx.x >> 6, lane = threadIdx.x & 63;
    int n = blockIdx.x * 4 + w;
    float x1 = X[(size_t)n * FIN + lane];
    float x2 = X[(size_t)n * FIN + 64 + lane];
    Xb[(size_t)n * FIN + lane] = __float2bfloat16(x1);
    Xb[(size_t)n * FIN + 64 + lane] = __float2bfloat16(x2);
    float pl[4], pr[4];
#pragma unroll
    for (int h = 0; h < 4; ++h) {
        pl[h] = x1 * wl[lane * 4 + h] + x2 * wl[(lane + 64) * 4 + h];
        pr[h] = x1 * wr[lane * 4 + h] + x2 * wr[(lane + 64) * 4 + h];
    }
#pragma unroll
    for (int off = 32; off > 0; off >>= 1) {
#pragma unroll
        for (int h = 0; h < 4; ++h) {
            pl[h] += __shfl_xor(pl[h], off);
            pr[h] += __shfl_xor(pr[h], off);
        }
    }
    if (lane == 0) {
        *reinterpret_cast<float4*>(el + (size_t)n * 4) = make_float4(pl[0], pl[1], pl[2], pl[3]);
        *reinterpret_cast<float4*>(er + (size_t)n * 4) = make_float4(pr[0], pr[1], pr[2], pr[3]);
    }
}

// 3-phase parallel exclusive scan of deg[50000] -> rowptr/cursor
__global__ __launch_bounds__(256) void scan1_k(const int* __restrict__ deg,
                                               int* __restrict__ rowptr, int* __restrict__ blksum) {
    __shared__ int wsum[4];
    int t = threadIdx.x, b = blockIdx.x;
    int i = b * 256 + t;
    int v = (i < N_NODES) ? deg[i] : 0;
    int lane = t & 63, w = t >> 6;
    int x = v;
#pragma unroll
    for (int off = 1; off < 64; off <<= 1) {
        int y = __shfl_up(x, off);
        if (lane >= off) x += y;
    }
    if (lane == 63) wsum[w] = x;
    __syncthreads();
    int wadd = 0;
    if (w > 0) wadd += wsum[0];
    if (w > 1) wadd += wsum[1];
    if (w > 2) wadd += wsum[2];
    int incl = x + wadd;
    if (i < N_NODES) rowptr[i] = incl - v;
    if (t == 255) blksum[b] = incl;
}

__global__ __launch_bounds__(256) void scan2_k(int* __restrict__ blksum) {
    __shared__ int wsum[4];
    int t = threadIdx.x;
    int v = (t < 196) ? blksum[t] : 0;
    int lane = t & 63, w = t >> 6;
    int x = v;
#pragma unroll
    for (int off = 1; off < 64; off <<= 1) {
        int y = __shfl_up(x, off);
        if (lane >= off) x += y;
    }
    if (lane == 63) wsum[w] = x;
    __syncthreads();
    int wadd = 0;
    if (w > 0) wadd += wsum[0];
    if (w > 1) wadd += wsum[1];
    if (w > 2) wadd += wsum[2];
    if (t < 196) blksum[t] = x + wadd - v;
}

__global__ __launch_bounds__(256) void scan3_k(const int* __restrict__ blksum,
                                               int* __restrict__ rowptr, int* __restrict__ cursor) {
    int b = blockIdx.x;
    int i = b * 256 + threadIdx.x;
    if (i < N_NODES) {
        int v = rowptr[i] + blksum[b];
        rowptr[i] = v;
        cursor[i] = v;
    }
    if (i == 0) rowptr[N_NODES] = N_EDGES;
}

__global__ void fill_k(const int* __restrict__ src, const int* __restrict__ dst,
                       int* __restrict__ cursor, int* __restrict__ csr) {
    int e = blockIdx.x * 256 + threadIdx.x;
    if (e < N_EDGES) {
        int pos = atomicAdd(&cursor[dst[e]], 1);
        csr[pos] = src[e];
    }
}

// ---------------- X-space aggregation v3: 16 nodes/block, 4-wide clamped + packed FMA ----------------
// AGG[n][h*128+c] = (1/den_h) sum_e p^h_e Xb[src_e][c]; lane owns 2 channels (4B), all 4 heads.
__global__ __launch_bounds__(1024) void aggX_k(const int* __restrict__ rowptr, const int* __restrict__ csr,
                                               const float* __restrict__ el, const float* __restrict__ er,
                                               const bf16* __restrict__ Xb, bf16* __restrict__ AGGb) {
    __shared__ int    ssrc[16][64];
    __shared__ float4 spe4[16][64];

    const int w = threadIdx.x >> 6, lane = threadIdx.x & 63;
    const int n = blockIdx.x * 16 + w;
    const int beg = rowptr[n];
    const int deg = rowptr[n + 1] - beg;
    const float4 ern = *reinterpret_cast<const float4*>(er + (size_t)n * 4);
    const char* Xbc = reinterpret_cast<const char*>(Xb);

    f32x2 acc[4] = {{0.f,0.f},{0.f,0.f},{0.f,0.f},{0.f,0.f}};
    float4 den = make_float4(0.f, 0.f, 0.f, 0.f);

    for (int base = 0; base < deg; base += 64) {
        const int cnt = min(64, deg - base);
        if (lane < cnt) {
            int s = csr[beg + base + lane];
            ssrc[w][lane] = s;
            float4 e4 = *reinterpret_cast<const float4*>(el + (size_t)s * 4);
            float4 p; float e;
            e = e4.x + ern.x; e = e > 0.f ? e : SLOPE * e; p.x = __expf(e);
            e = e4.y + ern.y; e = e > 0.f ? e : SLOPE * e; p.y = __expf(e);
            e = e4.z + ern.z; e = e > 0.f ? e : SLOPE * e; p.z = __expf(e);
            e = e4.w + ern.w; e = e > 0.f ? e : SLOPE * e; p.w = __expf(e);
            den.x += p.x; den.y += p.y; den.z += p.z; den.w += p.w;
            spe4[w][lane] = p;
        }
        asm volatile("s_waitcnt lgkmcnt(0)" ::: "memory");
        // 4-wide clamped batches: every edge batched, 4 outstanding loads
        for (int jj = 0; jj < cnt; jj += 4) {
            unsigned xv[4]; float4 pk[4];
#pragma unroll
            for (int k2 = 0; k2 < 4; ++k2) {
                int j2 = jj + k2;
                int jc = j2 < cnt ? j2 : cnt - 1;
                int s = ssrc[w][jc];
                xv[k2] = *reinterpret_cast<const unsigned*>(Xbc + (size_t)s * 256 + lane * 4);
                float4 p = spe4[w][jc];
                if (j2 >= cnt) p = make_float4(0.f, 0.f, 0.f, 0.f);
                pk[k2] = p;
            }
#pragma unroll
            for (int k2 = 0; k2 < 4; ++k2) {
                f32x2 x2 = {__uint_as_float(xv[k2] << 16), __uint_as_float(xv[k2] & 0xffff0000u)};
                acc[0] += pk[k2].x * x2;
                acc[1] += pk[k2].y * x2;
                acc[2] += pk[k2].z * x2;
                acc[3] += pk[k2].w * x2;
            }
        }
        asm volatile("s_waitcnt lgkmcnt(0)" ::: "memory");   // WAR guard before next chunk
    }

#pragma unroll
    for (int off = 32; off > 0; off >>= 1) {
        den.x += __shfl_xor(den.x, off);
        den.y += __shfl_xor(den.y, off);
        den.z += __shfl_xor(den.z, off);
        den.w += __shfl_xor(den.w, off);
    }
    float inv[4] = {0.f, 0.f, 0.f, 0.f};
    if (deg > 0) {
        inv[0] = 1.f / den.x; inv[1] = 1.f / den.y;
        inv[2] = 1.f / den.z; inv[3] = 1.f / den.w;
    }
#pragma unroll
    for (int h = 0; h < 4; ++h) {
        bf16x2 v = {(__bf16)(acc[h][0] * inv[h]), (__bf16)(acc[h][1] * inv[h])};
        *reinterpret_cast<bf16x2*>(AGGb + (size_t)n * 512 + h * 128 + lane * 2) = v;
    }
}

// ---------------- fused GEMM2 v3: coalesced Wfrag + tab epilogue ----------------
__global__ __launch_bounds__(256) void gemm2_k(
    const bf16* __restrict__ Xb, const bf16* __restrict__ AGGb,
    const bf16* __restrict__ Wfrag, const float* __restrict__ tab,
    const float* __restrict__ al2, const float* __restrict__ ar2,
    float* __restrict__ node2) {
    __shared__ __align__(16) char XS[32 * 256];    // 8 KB
    __shared__ __align__(16) char AGS[32 * 1024];  // 32 KB
    __shared__ float zsum[4][32][6];               // 3 KB

    const int t = threadIdx.x;
    const int w = t >> 6, lane = t & 63;
    const int cl = lane & 15, rg = lane >> 4;
    const int m0 = blockIdx.x * 32;

    // stage X: 32 rows x 256B
#pragma unroll
    for (int j = 0; j < 2; ++j) {
        int L = j * 4096 + t * 16;
        int row = L >> 8, col = L & 255;
        int grow = m0 + row; grow = grow < N_NODES ? grow : N_NODES - 1;
        bf16x8 v = *reinterpret_cast<const bf16x8*>(
            reinterpret_cast<const char*>(Xb) + (size_t)grow * 256 + col);
        int byte = (row * 256 + col) ^ ((row & 7) << 4);
        *reinterpret_cast<bf16x8*>(XS + byte) = v;
    }
    // stage AGG (all heads): 32 rows x 1024B
#pragma unroll
    for (int j = 0; j < 8; ++j) {
        int L = j * 4096 + t * 16;
        int row = L >> 10, col = L & 1023;
        int grow = m0 + row; grow = grow < N_NODES ? grow : N_NODES - 1;
        bf16x8 v = *reinterpret_cast<const bf16x8*>(
            reinterpret_cast<const char*>(AGGb) + (size_t)grow * 1024 + col);
        int byte = (row * 1024 + col) ^ ((row & 7) << 4);
        *reinterpret_cast<bf16x8*>(AGS + byte) = v;
    }
    __syncthreads();

    float z2p[2][3] = {}, r2p[2][3] = {};

#pragma unroll
    for (int ct = 0; ct < 8; ++ct) {
        const int unit = (w * 8 + ct) * 8;
        bf16x8 af[8];
#pragma unroll
        for (int ks = 0; ks < 8; ++ks)
            af[ks] = *reinterpret_cast<const bf16x8*>(
                reinterpret_cast<const char*>(Wfrag) + ((size_t)(unit + ks) * 64 + lane) * 16);
        const int gcl = w * 128 + ct * 16 + rg * 4;
        f32x4 t0[4], t1[4];
#pragma unroll
        for (int i = 0; i < 4; ++i) {
            t0[i] = *reinterpret_cast<const f32x4*>(tab + (size_t)(gcl + i) * 8);
            t1[i] = *reinterpret_cast<const f32x4*>(tab + (size_t)(gcl + i) * 8 + 4);
        }
#pragma unroll
        for (int mt = 0; mt < 2; ++mt) {
            int row = mt * 16 + cl;
            int swz = (row & 7) << 4;
            f32x4 a = {0.f, 0.f, 0.f, 0.f};
            // k 0..127: AGG head w
#pragma unroll
            for (int ks = 0; ks < 4; ++ks) {
                int byte = (row * 1024 + w * 256 + ks * 64 + rg * 16) ^ swz;
                bf16x8 bfr = *reinterpret_cast<const bf16x8*>(AGS + byte);
                a = __builtin_amdgcn_mfma_f32_16x16x32_bf16(af[ks], bfr, a, 0, 0, 0);
            }
            // k 128..255: X
#pragma unroll
            for (int ks = 0; ks < 4; ++ks) {
                int byte = (row * 256 + ks * 64 + rg * 16) ^ swz;
                bf16x8 bfr = *reinterpret_cast<const bf16x8*>(XS + byte);
                a = __builtin_amdgcn_mfma_f32_16x16x32_bf16(af[ks + 4], bfr, a, 0, 0, 0);
            }
#pragma unroll
            for (int i = 0; i < 4; ++i) {
                float hv = a[i] * t0[i][0] + t0[i][1];
                hv = hv > 0.f ? hv : (__expf(hv) - 1.f);
                z2p[mt][0] += hv * t0[i][2]; z2p[mt][1] += hv * t0[i][3]; z2p[mt][2] += hv * t1[i][0];
                r2p[mt][0] += hv * t1[i][1]; r2p[mt][1] += hv * t1[i][2]; r2p[mt][2] += hv * t1[i][3];
            }
        }
    }

    // reduce across rg (4 lanes share node cl per mt)
#pragma unroll
    for (int mt = 0; mt < 2; ++mt)
#pragma unroll
        for (int c = 0; c < 3; ++c) {
            z2p[mt][c] += __shfl_xor(z2p[mt][c], 16);
            z2p[mt][c] += __shfl_xor(z2p[mt][c], 32);
            r2p[mt][c] += __shfl_xor(r2p[mt][c], 16);
            r2p[mt][c] += __shfl_xor(r2p[mt][c], 32);
        }
    if (rg == 0) {
#pragma unroll
        for (int mt = 0; mt < 2; ++mt) {
            int nl = mt * 16 + cl;
            zsum[w][nl][0] = z2p[mt][0]; zsum[w][nl][1] = z2p[mt][1]; zsum[w][nl][2] = z2p[mt][2];
            zsum[w][nl][3] = r2p[mt][0]; zsum[w][nl][4] = r2p[mt][1]; zsum[w][nl][5] = r2p[mt][2];
        }
    }
    __syncthreads();
    if (t < 32) {
        float v[6];
#pragma unroll
        for (int c = 0; c < 6; ++c)
            v[c] = zsum[0][t][c] + zsum[1][t][c] + zsum[2][t][c] + zsum[3][t][c];
        int n = m0 + t;
        if (n < N_NODES) {
            float e2l = v[0] * al2[0] + v[1] * al2[1] + v[2] * al2[2];
            float e2r = v[0] * ar2[0] + v[1] * ar2[1] + v[2] * ar2[2];
            *reinterpret_cast<float4*>(node2 + (size_t)n * 8) = make_float4(v[0], v[1], v[2], e2l);
            *reinterpret_cast<float4*>(node2 + (size_t)n * 8 + 4) = make_float4(v[3], v[4], v[5], e2r);
        }
    }
}

// ---------------- layer-2 aggregation: wave-per-node ----------------
__global__ __launch_bounds__(256) void agg2_k(const int* __restrict__ rowptr, const int* __restrict__ csr,
                                              const float* __restrict__ node2,
                                              const float* __restrict__ b2, float* __restrict__ out) {
    int wv = threadIdx.x >> 6, lane = threadIdx.x & 63;
    int n = blockIdx.x * 4 + wv;
    int beg = rowptr[n], deg = rowptr[n + 1] - beg;
    float ern = node2[(size_t)n * 8 + 7];
    float den = 0.f, a0 = 0.f, a1 = 0.f, a2 = 0.f;
    for (int j = lane; j < deg; j += 64) {
        int s = csr[beg + j];
        float4 v = *reinterpret_cast<const float4*>(node2 + (size_t)s * 8);
        float e = v.w + ern;
        e = e > 0.f ? e : SLOPE * e;
        float p = __expf(e);
        den += p;
        a0 += p * v.x; a1 += p * v.y; a2 += p * v.z;
    }
#pragma unroll
    for (int off = 32; off > 0; off >>= 1) {
        den += __shfl_xor(den, off);
        a0 += __shfl_xor(a0, off); a1 += __shfl_xor(a1, off); a2 += __shfl_xor(a2, off);
    }
    if (lane == 0) {
        float inv = deg > 0 ? 1.f / den : 0.f;
        float4 r = *reinterpret_cast<const float4*>(node2 + (size_t)n * 8 + 4);
        out[(size_t)n * 3 + 0] = a0 * inv + r.x + b2[0];
        out[(size_t)n * 3 + 1] = a1 * inv + r.y + b2[1];
        out[(size_t)n * 3 + 2] = a2 * inv + r.z + b2[2];
    }
}

extern "C" void kernel_launch(void* const* d_in, const int* in_sizes, int n_in,
                              void* d_out, int out_size, void* d_ws, size_t ws_size,
                              hipStream_t stream) {
    const float* X     = (const float*)d_in[0];
    const int*   src   = (const int*)d_in[1];
    const int*   dst   = (const int*)d_in[2];
    const float* W1    = (const float*)d_in[3];
    const float* al1   = (const float*)d_in[4];
    const float* ar1   = (const float*)d_in[5];
    const float* b1    = (const float*)d_in[6];
    const float* Wres1 = (const float*)d_in[7];
    const float* bng   = (const float*)d_in[8];
    const float* bnb   = (const float*)d_in[9];
    const float* bnm   = (const float*)d_in[10];
    const float* bnv   = (const float*)d_in[11];
    const float* W2    = (const float*)d_in[12];
    const float* al2   = (const float*)d_in[13];
    const float* ar2   = (const float*)d_in[14];
    const float* b2    = (const float*)d_in[15];
    const float* Wres2 = (const float*)d_in[16];
    float* out = (float*)d_out;

    char* p = (char*)d_ws;
    auto carve = [&](size_t bytes) -> char* {
        char* r = p;
        p += (bytes + 255) & ~(size_t)255;
        return r;
    };
    bf16*  Wfrag  = (bf16*)carve((size_t)512 * 256 * 2);    // 256 KB fragment-ordered
    float* tab    = (float*)carve((size_t)512 * 8 * 4);     // 16 KB epilogue constants
    float* wl     = (float*)carve((size_t)FIN * 4 * 4);
    float* wr     = (float*)carve((size_t)FIN * 4 * 4);
    float* el     = (float*)carve((size_t)N_NODES * 4 * 4);
    float* er     = (float*)carve((size_t)N_NODES * 4 * 4);
    int*   deg    = (int*)carve((size_t)N_NODES * 4);
    int*   rowptr = (int*)carve((size_t)(N_NODES + 1) * 4);
    int*   cursor = (int*)carve((size_t)N_NODES * 4);
    int*   blksum = (int*)carve((size_t)256 * 4);
    int*   csr    = (int*)carve((size_t)N_EDGES * 4);
    bf16*  Xb     = (bf16*)carve((size_t)N_NODES * FIN * 2);
    bf16*  AGGb   = (bf16*)carve((size_t)N_NODES * 512 * 2);
    float* node2  = (float*)carve((size_t)N_NODES * 8 * 4);
    size_t need = (size_t)(p - (char*)d_ws);
    if (need > ws_size) {
        sentinel_k<<<(out_size + 255) / 256, 256, 0, stream>>>(out, out_size);
        return;
    }

    prep_k<<<196 + 64 + 16 + 2, 256, 0, stream>>>(W1, Wres1, al1, ar1, W2, Wres2, b1,
                                                  bnm, bnv, bng, bnb, Wfrag, tab, wl, wr, deg);
    eler_k<<<N_NODES / 4 + (N_EDGES + 255) / 256, 256, 0, stream>>>(X, wl, wr, el, er, Xb, dst, deg);
    scan1_k<<<196, 256, 0, stream>>>(deg, rowptr, blksum);
    scan2_k<<<1, 256, 0, stream>>>(blksum);
    scan3_k<<<196, 256, 0, stream>>>(blksum, rowptr, cursor);
    fill_k<<<(N_EDGES + 255) / 256, 256, 0, stream>>>(src, dst, cursor, csr);
    aggX_k<<<N_NODES / 16, 1024, 0, stream>>>(rowptr, csr, el, er, Xb, AGGb);
    gemm2_k<<<(N_NODES + 31) / 32, 256, 0, stream>>>(Xb, AGGb, Wfrag, tab, al2, ar2, node2);
    agg2_k<<<N_NODES / 4, 256, 0, stream>>>(rowptr, csr, node2, b2, out);
}